// Round 16
// baseline (177.783 us; speedup 1.0000x reference)
//
#include <hip/hip_runtime.h>

// MoEAttentionBlock r16: r14 champion + A-lead deepened to 2 phases
// (4 LDS pair-buffers, uniform vmcnt(12), 12 loads in flight). BN=64 both GEMMs.
// B=4 N=512 H=1024 NH=16 E=8 DH=64, T=2048.

typedef short short8 __attribute__((ext_vector_type(8)));
typedef float f32x4 __attribute__((ext_vector_type(4)));

constexpr int Bsz  = 4;
constexpr int Nseq = 512;
constexpr int Hdim = 1024;
constexpr int NHd  = 16;
constexpr int Ex   = 8;
constexpr int DHd  = 64;
constexpr int T    = Bsz * Nseq;   // 2048
constexpr int H3   = 3 * Hdim;     // 3072
constexpr int MAXT128 = 24;        // sum ceil(c_e/128) <= 16+8
constexpr int KB_N = 32;           // 32 K-tiles of 32
constexpr int NPH  = KB_N / 2;     // 16 phases of 64 k

__device__ inline unsigned short f2bf(float f) {
  union { float f; unsigned u; } v{f};
  unsigned r = v.u + 0x7fffu + ((v.u >> 16) & 1u);   // RNE
  return (unsigned short)(r >> 16);
}
__device__ inline float bf2f(unsigned short s) {
  union { unsigned u; float f; } v{(unsigned)s << 16};
  return v.f;
}
__device__ inline unsigned cvtpk2(float lo, float hi) {   // bf16(lo) | bf16(hi)<<16
  unsigned r;
  asm("v_cvt_pk_bf16_f32 %0, %1, %2" : "=v"(r) : "v"(lo), "v"(hi));
  return r;
}
__device__ inline void gl16(const unsigned short* g, unsigned short* l) {
  __builtin_amdgcn_global_load_lds(
      (const __attribute__((address_space(1))) unsigned int*)(g),
      (__attribute__((address_space(3))) unsigned int*)(l), 16, 0, 0);
}

// ---------------- init ------------------------------------------------------------
__global__ void init_kernel(int* counts) {
  if (threadIdx.x < Ex) counts[threadIdx.x] = 0;
}

// ---------------- gating + bf16 convert: 4 tokens/block ---------------------------
__global__ __launch_bounds__(256) void gate_kernel(
    const float* __restrict__ x, const float* __restrict__ wg,
    float* __restrict__ prob, int* __restrict__ expert, int* __restrict__ counts,
    unsigned short* __restrict__ Xb) {
  int t = blockIdx.x * 4 + (threadIdx.x >> 6);
  int l = threadIdx.x & 63;
  const float* xr = x + (size_t)t * Hdim;
  float acc[Ex] = {0, 0, 0, 0, 0, 0, 0, 0};
  for (int h = l; h < Hdim; h += 64) {
    float xv = xr[h];
    const float4* wr = (const float4*)(wg + (size_t)h * Ex);
    float4 w0 = wr[0], w1 = wr[1];
    acc[0] += xv * w0.x; acc[1] += xv * w0.y; acc[2] += xv * w0.z; acc[3] += xv * w0.w;
    acc[4] += xv * w1.x; acc[5] += xv * w1.y; acc[6] += xv * w1.z; acc[7] += xv * w1.w;
  }
  {
    const float4* s = (const float4*)(xr + l * 16);
    float4 f0 = s[0], f1 = s[1], f2 = s[2], f3 = s[3];
    unsigned q[8] = {cvtpk2(f0.x, f0.y), cvtpk2(f0.z, f0.w),
                     cvtpk2(f1.x, f1.y), cvtpk2(f1.z, f1.w),
                     cvtpk2(f2.x, f2.y), cvtpk2(f2.z, f2.w),
                     cvtpk2(f3.x, f3.y), cvtpk2(f3.z, f3.w)};
    uint4* d = (uint4*)(Xb + (size_t)t * Hdim + l * 16);
    d[0] = *(uint4*)&q[0];
    d[1] = *(uint4*)&q[4];
  }
#pragma unroll
  for (int e = 0; e < Ex; e++) {
#pragma unroll
    for (int off = 32; off > 0; off >>= 1) acc[e] += __shfl_down(acc[e], off);
  }
  if (l == 0) {
    float m = acc[0]; int mi = 0;
#pragma unroll
    for (int e = 1; e < Ex; e++) if (acc[e] > m) { m = acc[e]; mi = e; }  // first-max == jnp.argmax
    float s = 0.f;
#pragma unroll
    for (int e = 0; e < Ex; e++) s += expf(acc[e] - m);
    prob[t]   = 1.0f / s;
    expert[t] = mi;
    atomicAdd(&counts[mi], 1);
  }
}

// ---------------- offsets + BM=128 tile map ---------------------------------------
__global__ void offsets_kernel(const int* __restrict__ counts, int* offs, int* cursor,
                               int* meta, int* te, int* tr) {
  int o = 0, nt = 0;
  for (int e = 0; e < Ex; e++) {
    offs[e] = o; cursor[e] = o;
    int c = counts[e];
    for (int r = 0; r < c; r += 128) { te[nt] = e; tr[nt] = o + r; nt++; }
    o += c;
  }
  offs[Ex] = o;
  meta[0] = nt;
}

// ---------------- scatter ---------------------------------------------------------
__global__ __launch_bounds__(256) void scatter_kernel(
    const int* __restrict__ expert, int* cursor, int* __restrict__ perm) {
  int t = blockIdx.x * 256 + threadIdx.x;
  if (t < T) {
    int slot = atomicAdd(&cursor[expert[t]], 1);
    perm[slot] = t;
  }
}

// ---------------- W pre-tiler (unchanged r8) --------------------------------------
template <int NCOLS, int NCB>
__global__ __launch_bounds__(256) void wconv_kernel(const float* __restrict__ W,
                                                    unsigned short* __restrict__ Wt) {
  int ncb = blockIdx.x, kb = blockIdx.y, e = blockIdx.z;
  __shared__ float Ls[32 * 132];
  int tid = threadIdx.x;
  const float* src = W + ((size_t)e * Hdim + kb * 32) * NCOLS + ncb * 128;
  int r = tid >> 3, cb = (tid & 7) * 4;
#pragma unroll
  for (int i = 0; i < 4; i++) {
    float4 v = *(const float4*)(src + (size_t)r * NCOLS + cb + i * 32);
    *(float4*)&Ls[r * 132 + cb + i * 32] = v;
  }
  __syncthreads();
  unsigned short* dst = Wt + (((size_t)e * NCB + ncb) * KB_N + kb) * 4096;
#pragma unroll
  for (int h = 0; h < 2; h++) {
    int c = h * 256 + tid;
    int F = c >> 6, l4c = (c >> 4) & 3, l15c = c & 15;
    const float* col = &Ls[(8 * l4c) * 132 + F * 16 + l15c];
    unsigned q[4];
#pragma unroll
    for (int j = 0; j < 4; j++)
      q[j] = cvtpk2(col[(2 * j) * 132], col[(2 * j + 1) * 132]);
    *(uint4*)(dst + (size_t)c * 8) = *(uint4*)q;
  }
}

// ---------------- grouped GEMM v15: 2-K-step phases, A-lead 2, vmcnt(12) ----------
// BM=128 BN=64, 4 waves 2x2. Phase = 64 k: vmcnt(12)+barrier, 4 gl16 (A for
// phase p+2 -> pair (p+2)%4), 8 ds_read_b128, 16 MFMA, 4 B reg loads (B(p+2)).
// A LDS: 4 pairs x 16KB = 64KB. 12 loads in flight at every wait.
template <int BN>
__global__ __launch_bounds__(256) void moe_gemm_v15(
    const unsigned short* __restrict__ Xb, const unsigned short* __restrict__ Wt,
    const float* __restrict__ bias, const float* __restrict__ prob,
    const int* __restrict__ perm, const int* __restrict__ offs,
    const int* __restrict__ metap, const int* __restrict__ tile_e,
    const int* __restrict__ tile_r,
    unsigned short* __restrict__ Ybf, float* __restrict__ Yf, int Ncols) {
  constexpr int NF = BN / 32;            // 2
  int tIdx = blockIdx.y;
  if (tIdx >= metap[0]) return;
  int e = tile_e[tIdx], row0 = tile_r[tIdx];
  int rows = offs[e + 1] - row0; if (rows > 128) rows = 128;
  int col0 = blockIdx.x * BN;
  int ncb_n = Ncols >> 7;

  __shared__ unsigned short As[4 * 8192];   // [pair 0..3][tile 0/1][128*32]
  __shared__ int   tok_s[128];
  __shared__ float p_s[128];

  int tid = threadIdx.x;
  if (tid < 128) {
    int rr = tid < rows ? tid : rows - 1;
    int tok = perm[row0 + rr];
    tok_s[tid] = tok; p_s[tid] = prob[tok];
  }
  __syncthreads();

  int lane = tid & 63, wave = tid >> 6;
  int l15 = lane & 15, l4 = lane >> 4;
  int wr = wave >> 1, wc = wave & 1;
  int aslotr = l4 ^ ((l15 >> 1) & 3);

  // A gather sources (swizzled-slot scheme, verified since r7)
  int arow0 = wave * 16 + (lane >> 2);
  int arow1 = arow0 + 64;
  int aslot0 = (lane & 3) ^ ((arow0 >> 1) & 3);
  int aslot1 = (lane & 3) ^ ((arow1 >> 1) & 3);
  const unsigned short* ag0 = Xb + (size_t)tok_s[arow0] * Hdim + aslot0 * 8;
  const unsigned short* ag1 = Xb + (size_t)tok_s[arow1] * Hdim + aslot1 * 8;

  const unsigned short* btile = Wt + (((size_t)e * ncb_n + (col0 >> 7)) * KB_N) * 4096;
  int Fb = ((col0 & 127) >> 4) + wc * NF;
  const unsigned short* bfrag = btile + ((size_t)(Fb * 64 + lane)) * 8;

  f32x4 acc[4][NF] = {};
  short8 bq[2][2][NF];   // [phase parity][k-tile in phase][frag] — static

#define STAGEA(PH, PAIR)                                                           \
  {                                                                                \
    unsigned short* dA = As + (PAIR) * 8192;                                       \
    gl16(ag0 + (size_t)(2 * (PH)) * 32, dA + wave * 512);                          \
    gl16(ag1 + (size_t)(2 * (PH)) * 32, dA + 2048 + wave * 512);                   \
    gl16(ag0 + (size_t)(2 * (PH) + 1) * 32, dA + 4096 + wave * 512);               \
    gl16(ag1 + (size_t)(2 * (PH) + 1) * 32, dA + 4096 + 2048 + wave * 512);        \
  }

  // ---- prologue: A(0)->pair0, A(1)->pair1; B parities 0 (k0,k1), 1 (k2,k3) ----
  STAGEA(0, 0);
  STAGEA(1, 1);
  asm volatile("" ::: "memory");
#pragma unroll
  for (int t = 0; t < 2; t++)
#pragma unroll
    for (int n = 0; n < NF; n++)
      bq[0][t][n] = *(const short8*)(bfrag + (size_t)t * 4096 + n * 512);
#pragma unroll
  for (int t = 0; t < 2; t++)
#pragma unroll
    for (int n = 0; n < NF; n++)
      bq[1][t][n] = *(const short8*)(bfrag + (size_t)(2 + t) * 4096 + n * 512);
  asm volatile("" ::: "memory");

#define PHASE(PH, APAIR, BPAR)                                                     \
  {                                                                                \
    int kap = ((PH) + 2 < NPH) ? (PH) + 2 : NPH - 1;  /* A stage: +2 phases */     \
    int kbp = ((PH) + 2 < NPH) ? (PH) + 2 : NPH - 1;  /* B reload: +2 phases */    \
    asm volatile("s_waitcnt vmcnt(12)" ::: "memory");                              \
    __builtin_amdgcn_s_barrier();                                                  \
    asm volatile("" ::: "memory");                                                 \
    STAGEA(kap, ((APAIR) + 2) & 3);                                                \
    asm volatile("" ::: "memory");                                                 \
    _Pragma("unroll")                                                              \
    for (int t = 0; t < 2; t++) {                                                  \
      const unsigned short* rb = As + (APAIR) * 8192 + t * 4096;                   \
      short8 a[4];                                                                 \
      _Pragma("unroll")                                                            \
      for (int m = 0; m < 4; m++)                                                  \
        a[m] = *(const short8*)&rb[(wr * 64 + m * 16 + l15) * 32 + aslotr * 8];    \
      _Pragma("unroll")                                                            \
      for (int n = 0; n < NF; n++)                                                 \
        _Pragma("unroll")                                                          \
        for (int m = 0; m < 4; m++)                                                \
          acc[m][n] = __builtin_amdgcn_mfma_f32_16x16x32_bf16(                     \
              a[m], bq[BPAR][t][n], acc[m][n], 0, 0, 0);                           \
    }                                                                              \
    _Pragma("unroll")                                                              \
    for (int t = 0; t < 2; t++)                                                    \
      _Pragma("unroll")                                                            \
      for (int n = 0; n < NF; n++)                                                 \
        bq[BPAR][t][n] =                                                           \
            *(const short8*)(bfrag + (size_t)(2 * kbp + t) * 4096 + n * 512);      \
  }

  for (int ph = 0; ph < NPH; ph += 4) {
    PHASE(ph + 0, 0, 0);
    PHASE(ph + 1, 1, 1);
    PHASE(ph + 2, 2, 0);
    PHASE(ph + 3, 3, 1);
  }
#undef PHASE
#undef STAGEA
  asm volatile("s_waitcnt vmcnt(0)" ::: "memory");   // drain dummy tail stages

  // epilogue: C/D layout col=lane&15, row=(lane>>4)*4+reg  [m89]
#pragma unroll
  for (int n = 0; n < NF; n++) {
    int colg = col0 + wc * (NF * 16) + n * 16 + l15;
    float bv = bias[(size_t)e * Ncols + colg];
#pragma unroll
    for (int m = 0; m < 4; m++) {
#pragma unroll
      for (int r = 0; r < 4; r++) {
        int row = wr * 64 + m * 16 + l4 * 4 + r;
        if (row < rows) {
          int tok = tok_s[row];
          float o = (acc[m][n][r] + bv) * p_s[row];
          if (Ybf) Ybf[(size_t)tok * Ncols + colg] = f2bf(o);
          else     Yf [(size_t)tok * Ncols + colg] = o;
        }
      }
    }
  }
}

// ---------------- MFMA attention (r13: register-resident softmax) -----------------
__global__ __launch_bounds__(256) void attn_kernel(
    const unsigned short* __restrict__ qkvb, const int* __restrict__ attn_mask,
    const int* __restrict__ kp_mask, float* __restrict__ probs_out,
    unsigned short* __restrict__ ctxb) {
  int qt = blockIdx.x, h = blockIdx.y, b = blockIdx.z;
  int tid = threadIdx.x;

  __shared__ unsigned short Qs[32 * 72];
  __shared__ unsigned short KV[2][64 * 72];
  __shared__ unsigned short S[32 * 520];
  __shared__ float invs[32];

  int lane = tid & 63, wave = tid >> 6;
  int l15 = lane & 15, l4 = lane >> 4;

  {
    int r = tid >> 3, c = (tid & 7) * 8;
    int t = b * Nseq + qt * 32 + r;
    uint4 v = *(const uint4*)(qkvb + (size_t)t * H3 + h * DHd + c);
    unsigned short* u = (unsigned short*)&v;
    unsigned short tmp[8];
#pragma unroll
    for (int j = 0; j < 8; j++) tmp[j] = f2bf(bf2f(u[j]) * 0.125f);
    *(uint4*)&Qs[r * 72 + c] = *(uint4*)tmp;
  }

  int kr0 = tid >> 3, kc0 = (tid & 7) * 8;
  int kr1 = kr0 + 32;
  const unsigned short* kbase = qkvb + (size_t)(b * Nseq) * H3 + Hdim + h * DHd + kc0;
  uint4 rc0 = *(const uint4*)(kbase + (size_t)kr0 * H3);
  uint4 rc1 = *(const uint4*)(kbase + (size_t)kr1 * H3);
  int cur = 0;
  for (int kt = 0; kt < 8; kt++) {
    int kn = (kt + 1 < 8) ? kt + 1 : 7;
    uint4 nn0 = *(const uint4*)(kbase + (size_t)(kn * 64 + kr0) * H3);
    uint4 nn1 = *(const uint4*)(kbase + (size_t)(kn * 64 + kr1) * H3);
    *(uint4*)&KV[cur][kr0 * 72 + kc0] = rc0;
    *(uint4*)&KV[cur][kr1 * 72 + kc0] = rc1;
    asm volatile("s_waitcnt lgkmcnt(0)" ::: "memory");
    __builtin_amdgcn_s_barrier();
    asm volatile("" ::: "memory");

    f32x4 acc[2] = {};
#pragma unroll
    for (int kk = 0; kk < 2; kk++) {
      short8 bfr = *(const short8*)&KV[cur][(wave * 16 + l15) * 72 + kk * 32 + l4 * 8];
#pragma unroll
      for (int m = 0; m < 2; m++) {
        short8 afr = *(const short8*)&Qs[(m * 16 + l15) * 72 + kk * 32 + l4 * 8];
        acc[m] = __builtin_amdgcn_mfma_f32_16x16x32_bf16(afr, bfr, acc[m], 0, 0, 0);
      }
    }
    int key = kt * 64 + wave * 16 + l15;
#pragma unroll
    for (int m = 0; m < 2; m++) {
#pragma unroll
      for (int r = 0; r < 4; r++) {
        int row = m * 16 + l4 * 4 + r;
        S[row * 520 + key] = f2bf(acc[m][r]);
      }
    }
    rc0 = nn0; rc1 = nn1; cur ^= 1;
  }
  __syncthreads();

  float inv;
  int sr = tid >> 3, sg = tid & 7;
  float sv[8][8];
  {
    unsigned short* Srow = &S[sr * 520];
    const int* amrow = attn_mask + (qt * 32 + sr) * Nseq;
    const int* kprow = kp_mask + b * Nseq;
    float m = -3.0e38f;
#pragma unroll
    for (int i = 0; i < 8; i++) {
      int cb = (sg + 8 * i) * 8;
      uint4 v = *(const uint4*)&Srow[cb];
      unsigned short* u = (unsigned short*)&v;
      int4 a0 = *(const int4*)(amrow + cb);
      int4 a1 = *(const int4*)(amrow + cb + 4);
      int4 k0 = *(const int4*)(kprow + cb);
      int4 k1 = *(const int4*)(kprow + cb + 4);
      sv[i][0] = bf2f(u[0]) + ((a0.x | k0.x) ? -10000.0f : 0.0f);
      sv[i][1] = bf2f(u[1]) + ((a0.y | k0.y) ? -10000.0f : 0.0f);
      sv[i][2] = bf2f(u[2]) + ((a0.z | k0.z) ? -10000.0f : 0.0f);
      sv[i][3] = bf2f(u[3]) + ((a0.w | k0.w) ? -10000.0f : 0.0f);
      sv[i][4] = bf2f(u[4]) + ((a1.x | k1.x) ? -10000.0f : 0.0f);
      sv[i][5] = bf2f(u[5]) + ((a1.y | k1.y) ? -10000.0f : 0.0f);
      sv[i][6] = bf2f(u[6]) + ((a1.z | k1.z) ? -10000.0f : 0.0f);
      sv[i][7] = bf2f(u[7]) + ((a1.w | k1.w) ? -10000.0f : 0.0f);
#pragma unroll
      for (int j = 0; j < 8; j++) m = fmaxf(m, sv[i][j]);
    }
#pragma unroll
    for (int off = 1; off < 8; off <<= 1) m = fmaxf(m, __shfl_xor(m, off));
    float sum = 0.f;
#pragma unroll
    for (int i = 0; i < 8; i++) {
      int cb = (sg + 8 * i) * 8;
      unsigned short t2[8];
#pragma unroll
      for (int j = 0; j < 8; j++) {
        float p = expf(sv[i][j] - m);
        sv[i][j] = p;
        t2[j] = f2bf(p);
        sum += p;
      }
      *(uint4*)&Srow[cb] = *(uint4*)t2;
    }
#pragma unroll
    for (int off = 1; off < 8; off <<= 1) sum += __shfl_xor(sum, off);
    inv = 1.0f / sum;
    if (sg == 0) invs[sr] = inv;
  }
  __syncthreads();

  int kpair = tid & 31, vc = (tid >> 5) * 8;
  const unsigned short* vbase = qkvb + (size_t)(b * Nseq) * H3 + 2 * Hdim + h * DHd + vc;
  uint4 pv0 = *(const uint4*)(vbase + (size_t)(kpair * 2) * H3);
  uint4 pv1 = *(const uint4*)(vbase + (size_t)(kpair * 2 + 1) * H3);

  {
    float* dst = probs_out + (((size_t)(b * NHd + h) * Nseq + qt * 32 + sr) * Nseq);
#pragma unroll
    for (int i = 0; i < 8; i++) {
      int cb = (sg + 8 * i) * 8;
      float4 o0 = {sv[i][0] * inv, sv[i][1] * inv, sv[i][2] * inv, sv[i][3] * inv};
      float4 o1 = {sv[i][4] * inv, sv[i][5] * inv, sv[i][6] * inv, sv[i][7] * inv};
      *(float4*)(dst + cb)     = o0;
      *(float4*)(dst + cb + 4) = o1;
    }
  }

  f32x4 acc2[2] = {};
  cur = 0;
  for (int kt = 0; kt < 8; kt++) {
    int kn = (kt + 1 < 8) ? kt + 1 : 7;
    uint4 nv0 = *(const uint4*)(vbase + (size_t)(kn * 64 + kpair * 2) * H3);
    uint4 nv1 = *(const uint4*)(vbase + (size_t)(kn * 64 + kpair * 2 + 1) * H3);
    unsigned* a0 = (unsigned*)&pv0;
    unsigned* a1 = (unsigned*)&pv1;
#pragma unroll
    for (int i = 0; i < 4; i++) {
      unsigned lo = (a0[i] & 0xffffu) | (a1[i] << 16);
      unsigned hi = (a0[i] >> 16) | (a1[i] & 0xffff0000u);
      *(unsigned*)&KV[cur][(vc + 2 * i    ) * 72 + 2 * kpair] = lo;   // Vt[d][keypair]
      *(unsigned*)&KV[cur][(vc + 2 * i + 1) * 72 + 2 * kpair] = hi;
    }
    asm volatile("s_waitcnt lgkmcnt(0)" ::: "memory");
    __builtin_amdgcn_s_barrier();
    asm volatile("" ::: "memory");
#pragma unroll
    for (int kk = 0; kk < 2; kk++) {
      short8 bfr = *(const short8*)&KV[cur][(wave * 16 + l15) * 72 + kk * 32 + l4 * 8];
#pragma unroll
      for (int m = 0; m < 2; m++) {
        short8 pfr = *(const short8*)&S[(m * 16 + l15) * 520 + kt * 64 + kk * 32 + l4 * 8];
        acc2[m] = __builtin_amdgcn_mfma_f32_16x16x32_bf16(pfr, bfr, acc2[m], 0, 0, 0);
      }
    }
    pv0 = nv0; pv1 = nv1; cur ^= 1;
  }
#pragma unroll
  for (int m = 0; m < 2; m++) {
#pragma unroll
    for (int r = 0; r < 4; r++) {
      int row = m * 16 + l4 * 4 + r;
      int tq = b * Nseq + qt * 32 + row;
      ctxb[(size_t)tq * Hdim + h * DHd + wave * 16 + l15] = f2bf(acc2[m][r] * invs[row]);
    }
  }
}

// ---------------- host ------------------------------------------------------------
extern "C" void kernel_launch(void* const* d_in, const int* in_sizes, int n_in,
                              void* d_out, int out_size, void* d_ws, size_t ws_size,
                              hipStream_t stream) {
  const float* hidden   = (const float*)d_in[0];
  const int*   attn_m   = (const int*)d_in[1];
  const int*   kp_m     = (const int*)d_in[2];
  const float* w_gate   = (const float*)d_in[3];
  const float* w_qkv    = (const float*)d_in[4];
  const float* b_qkv    = (const float*)d_in[5];
  const float* w_dense  = (const float*)d_in[6];
  const float* b_dense  = (const float*)d_in[7];

  float* out       = (float*)d_out;                 // [T,H] fp32
  float* probs_out = out + (size_t)T * Hdim;        // [B,NH,N,N] fp32 (67 MB)

  // WtQ (50.3 MB) borrows the probs region: built+consumed BEFORE attn writes probs.
  unsigned short* WtQ = (unsigned short*)probs_out;

  float*          prob = (float*)d_ws;
  unsigned short* Xb   = (unsigned short*)(prob + 2048);
  unsigned short* qkvb = Xb + (size_t)T * Hdim;
  unsigned short* ctxb = qkvb + (size_t)T * H3;
  unsigned short* WtD  = ctxb + (size_t)T * Hdim;   // 16.8 MB
  int*   ip     = (int*)(WtD + (size_t)Ex * Hdim * Hdim);
  int*   expert = ip;
  int*   perm   = ip + T;
  int*   counts = ip + 2 * T;
  int*   offs   = counts + 8;
  int*   cursor = offs + 12;
  int*   meta   = cursor + 8;
  int*   te     = meta + 4;
  int*   tr     = te + MAXT128;

  init_kernel<<<1, 64, 0, stream>>>(counts);
  gate_kernel<<<T / 4, 256, 0, stream>>>(hidden, w_gate, prob, expert, counts, Xb);
  offsets_kernel<<<1, 1, 0, stream>>>(counts, offs, cursor, meta, te, tr);
  scatter_kernel<<<T / 256, 256, 0, stream>>>(expert, cursor, perm);

  wconv_kernel<H3, 24><<<dim3(24, KB_N, Ex), 256, 0, stream>>>(w_qkv, WtQ);
  wconv_kernel<Hdim, 8><<<dim3(8, KB_N, Ex), 256, 0, stream>>>(w_dense, WtD);

  moe_gemm_v15<64><<<dim3(H3 / 64, MAXT128), 256, 0, stream>>>(
      Xb, WtQ, b_qkv, prob, perm, offs, meta, te, tr, qkvb, nullptr, H3);
  attn_kernel<<<dim3(16, NHd, Bsz), 256, 0, stream>>>(qkvb, attn_m, kp_m, probs_out, ctxb);
  moe_gemm_v15<64><<<dim3(Hdim / 64, MAXT128), 256, 0, stream>>>(
      ctxb, WtD, b_dense, prob, perm, offs, meta, te, tr, nullptr, out, Hdim);
}

// Round 17
// 136.659 us; speedup vs baseline: 1.3009x; 1.3009x over previous
//
#include <hip/hip_runtime.h>

// MoEAttentionBlock r17: exact r14 champion + init/offsets/scatter fused into one
// route_kernel (LDS histogram + prefix + tile map + scatter); gate loses its
// global atomic. GEMM = v13 (2-K-step phases, BN=64). Attn = register softmax.
// B=4 N=512 H=1024 NH=16 E=8 DH=64, T=2048.

typedef short short8 __attribute__((ext_vector_type(8)));
typedef float f32x4 __attribute__((ext_vector_type(4)));

constexpr int Bsz  = 4;
constexpr int Nseq = 512;
constexpr int Hdim = 1024;
constexpr int NHd  = 16;
constexpr int Ex   = 8;
constexpr int DHd  = 64;
constexpr int T    = Bsz * Nseq;   // 2048
constexpr int H3   = 3 * Hdim;     // 3072
constexpr int MAXT128 = 24;        // sum ceil(c_e/128) <= 16+8
constexpr int KB_N = 32;           // 32 K-tiles of 32
constexpr int NPH  = KB_N / 2;     // 16 phases of 64 k

__device__ inline unsigned short f2bf(float f) {
  union { float f; unsigned u; } v{f};
  unsigned r = v.u + 0x7fffu + ((v.u >> 16) & 1u);   // RNE
  return (unsigned short)(r >> 16);
}
__device__ inline float bf2f(unsigned short s) {
  union { unsigned u; float f; } v{(unsigned)s << 16};
  return v.f;
}
__device__ inline unsigned cvtpk2(float lo, float hi) {   // bf16(lo) | bf16(hi)<<16
  unsigned r;
  asm("v_cvt_pk_bf16_f32 %0, %1, %2" : "=v"(r) : "v"(lo), "v"(hi));
  return r;
}
__device__ inline void gl16(const unsigned short* g, unsigned short* l) {
  __builtin_amdgcn_global_load_lds(
      (const __attribute__((address_space(1))) unsigned int*)(g),
      (__attribute__((address_space(3))) unsigned int*)(l), 16, 0, 0);
}

// ---------------- gating + bf16 convert (no global atomics) -----------------------
__global__ __launch_bounds__(64) void gate_kernel(
    const float* __restrict__ x, const float* __restrict__ wg,
    float* __restrict__ prob, int* __restrict__ expert,
    unsigned short* __restrict__ Xb) {
  int t = blockIdx.x;
  int l = threadIdx.x;
  const float* xr = x + (size_t)t * Hdim;
  float acc[Ex] = {0, 0, 0, 0, 0, 0, 0, 0};
  for (int h = l; h < Hdim; h += 64) {
    float xv = xr[h];
    const float4* wr = (const float4*)(wg + (size_t)h * Ex);
    float4 w0 = wr[0], w1 = wr[1];
    acc[0] += xv * w0.x; acc[1] += xv * w0.y; acc[2] += xv * w0.z; acc[3] += xv * w0.w;
    acc[4] += xv * w1.x; acc[5] += xv * w1.y; acc[6] += xv * w1.z; acc[7] += xv * w1.w;
  }
  {
    const float4* s = (const float4*)(xr + l * 16);
    float4 f0 = s[0], f1 = s[1], f2 = s[2], f3 = s[3];
    unsigned q[8] = {cvtpk2(f0.x, f0.y), cvtpk2(f0.z, f0.w),
                     cvtpk2(f1.x, f1.y), cvtpk2(f1.z, f1.w),
                     cvtpk2(f2.x, f2.y), cvtpk2(f2.z, f2.w),
                     cvtpk2(f3.x, f3.y), cvtpk2(f3.z, f3.w)};
    uint4* d = (uint4*)(Xb + (size_t)t * Hdim + l * 16);
    d[0] = *(uint4*)&q[0];
    d[1] = *(uint4*)&q[4];
  }
#pragma unroll
  for (int e = 0; e < Ex; e++) {
#pragma unroll
    for (int off = 32; off > 0; off >>= 1) acc[e] += __shfl_down(acc[e], off);
  }
  if (l == 0) {
    float m = acc[0]; int mi = 0;
#pragma unroll
    for (int e = 1; e < Ex; e++) if (acc[e] > m) { m = acc[e]; mi = e; }  // first-max == jnp.argmax
    float s = 0.f;
#pragma unroll
    for (int e = 0; e < Ex; e++) s += expf(acc[e] - m);
    prob[t]   = 1.0f / s;
    expert[t] = mi;
  }
}

// ---------------- route: histogram + offsets + BM=128 tile map + scatter ----------
__global__ __launch_bounds__(256) void route_kernel(
    const int* __restrict__ expert, int* offs, int* meta, int* te, int* tr,
    int* __restrict__ perm) {
  __shared__ int cnt[Ex];
  __shared__ int cur[Ex];
  int tid = threadIdx.x;
  if (tid < Ex) cnt[tid] = 0;
  __syncthreads();
  for (int t = tid; t < T; t += 256) atomicAdd(&cnt[expert[t]], 1);
  __syncthreads();
  if (tid == 0) {
    int o = 0, nt = 0;
    for (int e = 0; e < Ex; e++) {
      offs[e] = o; cur[e] = o;
      int c = cnt[e];
      for (int r = 0; r < c; r += 128) { te[nt] = e; tr[nt] = o + r; nt++; }
      o += c;
    }
    offs[Ex] = o;
    meta[0] = nt;
  }
  __syncthreads();
  for (int t = tid; t < T; t += 256) {
    int slot = atomicAdd(&cur[expert[t]], 1);
    perm[slot] = t;
  }
}

// ---------------- W pre-tiler (unchanged r8) --------------------------------------
// Wt chunk: [e][ncb][kb][F(8)][lane(64)] short8; (F,lane) holds
// W[k=kb*32+8*(lane>>4)+j][col=ncb*128+F*16+(lane&15)] — MFMA B-frag order.
template <int NCOLS, int NCB>
__global__ __launch_bounds__(256) void wconv_kernel(const float* __restrict__ W,
                                                    unsigned short* __restrict__ Wt) {
  int ncb = blockIdx.x, kb = blockIdx.y, e = blockIdx.z;
  __shared__ float Ls[32 * 132];
  int tid = threadIdx.x;
  const float* src = W + ((size_t)e * Hdim + kb * 32) * NCOLS + ncb * 128;
  int r = tid >> 3, cb = (tid & 7) * 4;
#pragma unroll
  for (int i = 0; i < 4; i++) {
    float4 v = *(const float4*)(src + (size_t)r * NCOLS + cb + i * 32);
    *(float4*)&Ls[r * 132 + cb + i * 32] = v;
  }
  __syncthreads();
  unsigned short* dst = Wt + (((size_t)e * NCB + ncb) * KB_N + kb) * 4096;
#pragma unroll
  for (int h = 0; h < 2; h++) {
    int c = h * 256 + tid;
    int F = c >> 6, l4c = (c >> 4) & 3, l15c = c & 15;
    const float* col = &Ls[(8 * l4c) * 132 + F * 16 + l15c];
    unsigned q[4];
#pragma unroll
    for (int j = 0; j < 4; j++)
      q[j] = cvtpk2(col[(2 * j) * 132], col[(2 * j + 1) * 132]);
    *(uint4*)(dst + (size_t)c * 8) = *(uint4*)q;
  }
}

// ---------------- grouped GEMM v13 (r14 champion): 2-K-step phases ----------------
// BM=128 BN=64, 4 waves 2x2. Phase = 64 k: one vmcnt(4)+lgkmcnt(0)+barrier,
// 4 gl16 (A next phase -> opposite pair), 8 ds_read_b128, 16 MFMA, 4 B reg
// loads (2-phase lead). A LDS: 2 pairs x 16KB = 32KB.
template <int BN>
__global__ __launch_bounds__(256) void moe_gemm_v13(
    const unsigned short* __restrict__ Xb, const unsigned short* __restrict__ Wt,
    const float* __restrict__ bias, const float* __restrict__ prob,
    const int* __restrict__ perm, const int* __restrict__ offs,
    const int* __restrict__ metap, const int* __restrict__ tile_e,
    const int* __restrict__ tile_r,
    unsigned short* __restrict__ Ybf, float* __restrict__ Yf, int Ncols) {
  constexpr int NF = BN / 32;            // 2 B-frags per wave
  int tIdx = blockIdx.y;
  if (tIdx >= metap[0]) return;
  int e = tile_e[tIdx], row0 = tile_r[tIdx];
  int rows = offs[e + 1] - row0; if (rows > 128) rows = 128;
  int col0 = blockIdx.x * BN;
  int ncb_n = Ncols >> 7;

  __shared__ unsigned short As[2 * 8192];   // [pair][tile 0/1][128*32]
  __shared__ int   tok_s[128];
  __shared__ float p_s[128];

  int tid = threadIdx.x;
  if (tid < 128) {
    int rr = tid < rows ? tid : rows - 1;
    int tok = perm[row0 + rr];
    tok_s[tid] = tok; p_s[tid] = prob[tok];
  }
  __syncthreads();

  int lane = tid & 63, wave = tid >> 6;
  int l15 = lane & 15, l4 = lane >> 4;
  int wr = wave >> 1, wc = wave & 1;
  int aslotr = l4 ^ ((l15 >> 1) & 3);

  // A gather sources (swizzled-slot scheme, verified since r7)
  int arow0 = wave * 16 + (lane >> 2);
  int arow1 = arow0 + 64;
  int aslot0 = (lane & 3) ^ ((arow0 >> 1) & 3);
  int aslot1 = (lane & 3) ^ ((arow1 >> 1) & 3);
  const unsigned short* ag0 = Xb + (size_t)tok_s[arow0] * Hdim + aslot0 * 8;
  const unsigned short* ag1 = Xb + (size_t)tok_s[arow1] * Hdim + aslot1 * 8;

  const unsigned short* btile = Wt + (((size_t)e * ncb_n + (col0 >> 7)) * KB_N) * 4096;
  int Fb = ((col0 & 127) >> 4) + wc * NF;
  const unsigned short* bfrag = btile + ((size_t)(Fb * 64 + lane)) * 8;

  f32x4 acc[4][NF] = {};
  short8 bq[2][2][NF];   // [phase parity][k-tile in phase][frag] — all static

  // ---- prologue: A(phase0)->pair0, B parities 0 (k0,k1) and 1 (k2,k3) ----
  gl16(ag0 + 0 * 32, As + 0 + wave * 512);
  gl16(ag1 + 0 * 32, As + 2048 + wave * 512);
  gl16(ag0 + 1 * 32, As + 4096 + wave * 512);
  gl16(ag1 + 1 * 32, As + 4096 + 2048 + wave * 512);
  asm volatile("" ::: "memory");
#pragma unroll
  for (int t = 0; t < 2; t++)
#pragma unroll
    for (int n = 0; n < NF; n++)
      bq[0][t][n] = *(const short8*)(bfrag + (size_t)t * 4096 + n * 512);
#pragma unroll
  for (int t = 0; t < 2; t++)
#pragma unroll
    for (int n = 0; n < NF; n++)
      bq[1][t][n] = *(const short8*)(bfrag + (size_t)(2 + t) * 4096 + n * 512);
  asm volatile("" ::: "memory");

#define PHASE(PH, PAR)                                                             \
  {                                                                                \
    int kap = ((PH) + 1 < NPH) ? (PH) + 1 : NPH - 1;  /* A stage: next phase */    \
    int kbp = ((PH) + 2 < NPH) ? (PH) + 2 : NPH - 1;  /* B reload: +2 phases */    \
    asm volatile("s_waitcnt vmcnt(4) lgkmcnt(0)" ::: "memory");                    \
    __builtin_amdgcn_s_barrier();                                                  \
    asm volatile("" ::: "memory");                                                 \
    unsigned short* dA = As + ((PAR) ^ 1) * 8192;                                  \
    gl16(ag0 + (size_t)(2 * kap) * 32, dA + wave * 512);                           \
    gl16(ag1 + (size_t)(2 * kap) * 32, dA + 2048 + wave * 512);                    \
    gl16(ag0 + (size_t)(2 * kap + 1) * 32, dA + 4096 + wave * 512);                \
    gl16(ag1 + (size_t)(2 * kap + 1) * 32, dA + 4096 + 2048 + wave * 512);         \
    asm volatile("" ::: "memory");                                                 \
    _Pragma("unroll")                                                              \
    for (int t = 0; t < 2; t++) {                                                  \
      const unsigned short* rb = As + (PAR) * 8192 + t * 4096;                     \
      short8 a[4];                                                                 \
      _Pragma("unroll")                                                            \
      for (int m = 0; m < 4; m++)                                                  \
        a[m] = *(const short8*)&rb[(wr * 64 + m * 16 + l15) * 32 + aslotr * 8];    \
      _Pragma("unroll")                                                            \
      for (int n = 0; n < NF; n++)                                                 \
        _Pragma("unroll")                                                          \
        for (int m = 0; m < 4; m++)                                                \
          acc[m][n] = __builtin_amdgcn_mfma_f32_16x16x32_bf16(                     \
              a[m], bq[PAR][t][n], acc[m][n], 0, 0, 0);                            \
    }                                                                              \
    _Pragma("unroll")                                                              \
    for (int t = 0; t < 2; t++)                                                    \
      _Pragma("unroll")                                                            \
      for (int n = 0; n < NF; n++)                                                 \
        bq[PAR][t][n] =                                                            \
            *(const short8*)(bfrag + (size_t)(2 * kbp + t) * 4096 + n * 512);      \
  }

  for (int ph = 0; ph < NPH; ph += 2) {
    PHASE(ph, 0);
    PHASE(ph + 1, 1);
  }
#undef PHASE
  asm volatile("s_waitcnt vmcnt(0)" ::: "memory");   // drain dummy tail stages

  // epilogue: C/D layout col=lane&15, row=(lane>>4)*4+reg  [m89]
#pragma unroll
  for (int n = 0; n < NF; n++) {
    int colg = col0 + wc * (NF * 16) + n * 16 + l15;
    float bv = bias[(size_t)e * Ncols + colg];
#pragma unroll
    for (int m = 0; m < 4; m++) {
#pragma unroll
      for (int r = 0; r < 4; r++) {
        int row = wr * 64 + m * 16 + l4 * 4 + r;
        if (row < rows) {
          int tok = tok_s[row];
          float o = (acc[m][n][r] + bv) * p_s[row];
          if (Ybf) Ybf[(size_t)tok * Ncols + colg] = f2bf(o);
          else     Yf [(size_t)tok * Ncols + colg] = o;
        }
      }
    }
  }
}

// ---------------- MFMA attention (r13: register-resident softmax) -----------------
__global__ __launch_bounds__(256) void attn_kernel(
    const unsigned short* __restrict__ qkvb, const int* __restrict__ attn_mask,
    const int* __restrict__ kp_mask, float* __restrict__ probs_out,
    unsigned short* __restrict__ ctxb) {
  int qt = blockIdx.x, h = blockIdx.y, b = blockIdx.z;
  int tid = threadIdx.x;

  __shared__ unsigned short Qs[32 * 72];
  __shared__ unsigned short KV[2][64 * 72];
  __shared__ unsigned short S[32 * 520];
  __shared__ float invs[32];

  int lane = tid & 63, wave = tid >> 6;
  int l15 = lane & 15, l4 = lane >> 4;

  {
    int r = tid >> 3, c = (tid & 7) * 8;
    int t = b * Nseq + qt * 32 + r;
    uint4 v = *(const uint4*)(qkvb + (size_t)t * H3 + h * DHd + c);
    unsigned short* u = (unsigned short*)&v;
    unsigned short tmp[8];
#pragma unroll
    for (int j = 0; j < 8; j++) tmp[j] = f2bf(bf2f(u[j]) * 0.125f);
    *(uint4*)&Qs[r * 72 + c] = *(uint4*)tmp;
  }

  int kr0 = tid >> 3, kc0 = (tid & 7) * 8;
  int kr1 = kr0 + 32;
  const unsigned short* kbase = qkvb + (size_t)(b * Nseq) * H3 + Hdim + h * DHd + kc0;
  uint4 rc0 = *(const uint4*)(kbase + (size_t)kr0 * H3);
  uint4 rc1 = *(const uint4*)(kbase + (size_t)kr1 * H3);
  int cur = 0;
  for (int kt = 0; kt < 8; kt++) {
    int kn = (kt + 1 < 8) ? kt + 1 : 7;
    uint4 nn0 = *(const uint4*)(kbase + (size_t)(kn * 64 + kr0) * H3);
    uint4 nn1 = *(const uint4*)(kbase + (size_t)(kn * 64 + kr1) * H3);
    *(uint4*)&KV[cur][kr0 * 72 + kc0] = rc0;
    *(uint4*)&KV[cur][kr1 * 72 + kc0] = rc1;
    asm volatile("s_waitcnt lgkmcnt(0)" ::: "memory");
    __builtin_amdgcn_s_barrier();
    asm volatile("" ::: "memory");

    f32x4 acc[2] = {};
#pragma unroll
    for (int kk = 0; kk < 2; kk++) {
      short8 bfr = *(const short8*)&KV[cur][(wave * 16 + l15) * 72 + kk * 32 + l4 * 8];
#pragma unroll
      for (int m = 0; m < 2; m++) {
        short8 afr = *(const short8*)&Qs[(m * 16 + l15) * 72 + kk * 32 + l4 * 8];
        acc[m] = __builtin_amdgcn_mfma_f32_16x16x32_bf16(afr, bfr, acc[m], 0, 0, 0);
      }
    }
    int key = kt * 64 + wave * 16 + l15;
#pragma unroll
    for (int m = 0; m < 2; m++) {
#pragma unroll
      for (int r = 0; r < 4; r++) {
        int row = m * 16 + l4 * 4 + r;
        S[row * 520 + key] = f2bf(acc[m][r]);
      }
    }
    rc0 = nn0; rc1 = nn1; cur ^= 1;
  }
  __syncthreads();

  float inv;
  int sr = tid >> 3, sg = tid & 7;
  float sv[8][8];
  {
    unsigned short* Srow = &S[sr * 520];
    const int* amrow = attn_mask + (qt * 32 + sr) * Nseq;
    const int* kprow = kp_mask + b * Nseq;
    float m = -3.0e38f;
#pragma unroll
    for (int i = 0; i < 8; i++) {
      int cb = (sg + 8 * i) * 8;
      uint4 v = *(const uint4*)&Srow[cb];
      unsigned short* u = (unsigned short*)&v;
      int4 a0 = *(const int4*)(amrow + cb);
      int4 a1 = *(const int4*)(amrow + cb + 4);
      int4 k0 = *(const int4*)(kprow + cb);
      int4 k1 = *(const int4*)(kprow + cb + 4);
      sv[i][0] = bf2f(u[0]) + ((a0.x | k0.x) ? -10000.0f : 0.0f);
      sv[i][1] = bf2f(u[1]) + ((a0.y | k0.y) ? -10000.0f : 0.0f);
      sv[i][2] = bf2f(u[2]) + ((a0.z | k0.z) ? -10000.0f : 0.0f);
      sv[i][3] = bf2f(u[3]) + ((a0.w | k0.w) ? -10000.0f : 0.0f);
      sv[i][4] = bf2f(u[4]) + ((a1.x | k1.x) ? -10000.0f : 0.0f);
      sv[i][5] = bf2f(u[5]) + ((a1.y | k1.y) ? -10000.0f : 0.0f);
      sv[i][6] = bf2f(u[6]) + ((a1.z | k1.z) ? -10000.0f : 0.0f);
      sv[i][7] = bf2f(u[7]) + ((a1.w | k1.w) ? -10000.0f : 0.0f);
#pragma unroll
      for (int j = 0; j < 8; j++) m = fmaxf(m, sv[i][j]);
    }
#pragma unroll
    for (int off = 1; off < 8; off <<= 1) m = fmaxf(m, __shfl_xor(m, off));
    float sum = 0.f;
#pragma unroll
    for (int i = 0; i < 8; i++) {
      int cb = (sg + 8 * i) * 8;
      unsigned short t2[8];
#pragma unroll
      for (int j = 0; j < 8; j++) {
        float p = expf(sv[i][j] - m);
        sv[i][j] = p;
        t2[j] = f2bf(p);
        sum += p;
      }
      *(uint4*)&Srow[cb] = *(uint4*)t2;
    }
#pragma unroll
    for (int off = 1; off < 8; off <<= 1) sum += __shfl_xor(sum, off);
    inv = 1.0f / sum;
    if (sg == 0) invs[sr] = inv;
  }
  __syncthreads();

  int kpair = tid & 31, vc = (tid >> 5) * 8;
  const unsigned short* vbase = qkvb + (size_t)(b * Nseq) * H3 + 2 * Hdim + h * DHd + vc;
  uint4 pv0 = *(const uint4*)(vbase + (size_t)(kpair * 2) * H3);
  uint4 pv1 = *(const uint4*)(vbase + (size_t)(kpair * 2 + 1) * H3);

  {
    float* dst = probs_out + (((size_t)(b * NHd + h) * Nseq + qt * 32 + sr) * Nseq);
#pragma unroll
    for (int i = 0; i < 8; i++) {
      int cb = (sg + 8 * i) * 8;
      float4 o0 = {sv[i][0] * inv, sv[i][1] * inv, sv[i][2] * inv, sv[i][3] * inv};
      float4 o1 = {sv[i][4] * inv, sv[i][5] * inv, sv[i][6] * inv, sv[i][7] * inv};
      *(float4*)(dst + cb)     = o0;
      *(float4*)(dst + cb + 4) = o1;
    }
  }

  f32x4 acc2[2] = {};
  cur = 0;
  for (int kt = 0; kt < 8; kt++) {
    int kn = (kt + 1 < 8) ? kt + 1 : 7;
    uint4 nv0 = *(const uint4*)(vbase + (size_t)(kn * 64 + kpair * 2) * H3);
    uint4 nv1 = *(const uint4*)(vbase + (size_t)(kn * 64 + kpair * 2 + 1) * H3);
    unsigned* a0 = (unsigned*)&pv0;
    unsigned* a1 = (unsigned*)&pv1;
#pragma unroll
    for (int i = 0; i < 4; i++) {
      unsigned lo = (a0[i] & 0xffffu) | (a1[i] << 16);
      unsigned hi = (a0[i] >> 16) | (a1[i] & 0xffff0000u);
      *(unsigned*)&KV[cur][(vc + 2 * i    ) * 72 + 2 * kpair] = lo;   // Vt[d][keypair]
      *(unsigned*)&KV[cur][(vc + 2 * i + 1) * 72 + 2 * kpair] = hi;
    }
    asm volatile("s_waitcnt lgkmcnt(0)" ::: "memory");
    __builtin_amdgcn_s_barrier();
    asm volatile("" ::: "memory");
#pragma unroll
    for (int kk = 0; kk < 2; kk++) {
      short8 bfr = *(const short8*)&KV[cur][(wave * 16 + l15) * 72 + kk * 32 + l4 * 8];
#pragma unroll
      for (int m = 0; m < 2; m++) {
        short8 pfr = *(const short8*)&S[(m * 16 + l15) * 520 + kt * 64 + kk * 32 + l4 * 8];
        acc2[m] = __builtin_amdgcn_mfma_f32_16x16x32_bf16(pfr, bfr, acc2[m], 0, 0, 0);
      }
    }
    pv0 = nv0; pv1 = nv1; cur ^= 1;
  }
#pragma unroll
  for (int m = 0; m < 2; m++) {
#pragma unroll
    for (int r = 0; r < 4; r++) {
      int row = m * 16 + l4 * 4 + r;
      int tq = b * Nseq + qt * 32 + row;
      ctxb[(size_t)tq * Hdim + h * DHd + wave * 16 + l15] = f2bf(acc2[m][r] * invs[row]);
    }
  }
}

// ---------------- host ------------------------------------------------------------
extern "C" void kernel_launch(void* const* d_in, const int* in_sizes, int n_in,
                              void* d_out, int out_size, void* d_ws, size_t ws_size,
                              hipStream_t stream) {
  const float* hidden   = (const float*)d_in[0];
  const int*   attn_m   = (const int*)d_in[1];
  const int*   kp_m     = (const int*)d_in[2];
  const float* w_gate   = (const float*)d_in[3];
  const float* w_qkv    = (const float*)d_in[4];
  const float* b_qkv    = (const float*)d_in[5];
  const float* w_dense  = (const float*)d_in[6];
  const float* b_dense  = (const float*)d_in[7];

  float* out       = (float*)d_out;                 // [T,H] fp32
  float* probs_out = out + (size_t)T * Hdim;        // [B,NH,N,N] fp32 (67 MB)

  // WtQ (50.3 MB) borrows the probs region: built+consumed BEFORE attn writes probs.
  unsigned short* WtQ = (unsigned short*)probs_out;

  float*          prob = (float*)d_ws;
  unsigned short* Xb   = (unsigned short*)(prob + 2048);
  unsigned short* qkvb = Xb + (size_t)T * Hdim;
  unsigned short* ctxb = qkvb + (size_t)T * H3;
  unsigned short* WtD  = ctxb + (size_t)T * Hdim;   // 16.8 MB
  int*   ip     = (int*)(WtD + (size_t)Ex * Hdim * Hdim);
  int*   expert = ip;
  int*   perm   = ip + T;
  int*   offs   = ip + 2 * T;
  int*   meta   = offs + 12;
  int*   te     = meta + 4;
  int*   tr     = te + MAXT128;

  gate_kernel<<<T, 64, 0, stream>>>(hidden, w_gate, prob, expert, Xb);
  route_kernel<<<1, 256, 0, stream>>>(expert, offs, meta, te, tr, perm);

  wconv_kernel<H3, 24><<<dim3(24, KB_N, Ex), 256, 0, stream>>>(w_qkv, WtQ);
  wconv_kernel<Hdim, 8><<<dim3(8, KB_N, Ex), 256, 0, stream>>>(w_dense, WtD);

  moe_gemm_v13<64><<<dim3(H3 / 64, MAXT128), 256, 0, stream>>>(
      Xb, WtQ, b_qkv, prob, perm, offs, meta, te, tr, qkvb, nullptr, H3);
  attn_kernel<<<dim3(16, NHd, Bsz), 256, 0, stream>>>(qkvb, attn_m, kp_m, probs_out, ctxb);
  moe_gemm_v13<64><<<dim3(Hdim / 64, MAXT128), 256, 0, stream>>>(
      ctxb, WtD, b_dense, prob, perm, offs, meta, te, tr, nullptr, out, Hdim);
}

// Round 18
// 131.374 us; speedup vs baseline: 1.3533x; 1.0402x over previous
//
#include <hip/hip_runtime.h>

// MoEAttentionBlock r18: r17 champion with wconv(QKV)+wconv(dense)+route fused
// into one prep_kernel — 5 launches total. All math byte-identical to r17.
// B=4 N=512 H=1024 NH=16 E=8 DH=64, T=2048.

typedef short short8 __attribute__((ext_vector_type(8)));
typedef float f32x4 __attribute__((ext_vector_type(4)));

constexpr int Bsz  = 4;
constexpr int Nseq = 512;
constexpr int Hdim = 1024;
constexpr int NHd  = 16;
constexpr int Ex   = 8;
constexpr int DHd  = 64;
constexpr int T    = Bsz * Nseq;   // 2048
constexpr int H3   = 3 * Hdim;     // 3072
constexpr int MAXT128 = 24;        // sum ceil(c_e/128) <= 16+8
constexpr int KB_N = 32;           // 32 K-tiles of 32
constexpr int NPH  = KB_N / 2;     // 16 phases of 64 k

__device__ inline unsigned short f2bf(float f) {
  union { float f; unsigned u; } v{f};
  unsigned r = v.u + 0x7fffu + ((v.u >> 16) & 1u);   // RNE
  return (unsigned short)(r >> 16);
}
__device__ inline float bf2f(unsigned short s) {
  union { unsigned u; float f; } v{(unsigned)s << 16};
  return v.f;
}
__device__ inline unsigned cvtpk2(float lo, float hi) {   // bf16(lo) | bf16(hi)<<16
  unsigned r;
  asm("v_cvt_pk_bf16_f32 %0, %1, %2" : "=v"(r) : "v"(lo), "v"(hi));
  return r;
}
__device__ inline void gl16(const unsigned short* g, unsigned short* l) {
  __builtin_amdgcn_global_load_lds(
      (const __attribute__((address_space(1))) unsigned int*)(g),
      (__attribute__((address_space(3))) unsigned int*)(l), 16, 0, 0);
}

// ---------------- gating + bf16 convert (no global atomics) -----------------------
__global__ __launch_bounds__(64) void gate_kernel(
    const float* __restrict__ x, const float* __restrict__ wg,
    float* __restrict__ prob, int* __restrict__ expert,
    unsigned short* __restrict__ Xb) {
  int t = blockIdx.x;
  int l = threadIdx.x;
  const float* xr = x + (size_t)t * Hdim;
  float acc[Ex] = {0, 0, 0, 0, 0, 0, 0, 0};
  for (int h = l; h < Hdim; h += 64) {
    float xv = xr[h];
    const float4* wr = (const float4*)(wg + (size_t)h * Ex);
    float4 w0 = wr[0], w1 = wr[1];
    acc[0] += xv * w0.x; acc[1] += xv * w0.y; acc[2] += xv * w0.z; acc[3] += xv * w0.w;
    acc[4] += xv * w1.x; acc[5] += xv * w1.y; acc[6] += xv * w1.z; acc[7] += xv * w1.w;
  }
  {
    const float4* s = (const float4*)(xr + l * 16);
    float4 f0 = s[0], f1 = s[1], f2 = s[2], f3 = s[3];
    unsigned q[8] = {cvtpk2(f0.x, f0.y), cvtpk2(f0.z, f0.w),
                     cvtpk2(f1.x, f1.y), cvtpk2(f1.z, f1.w),
                     cvtpk2(f2.x, f2.y), cvtpk2(f2.z, f2.w),
                     cvtpk2(f3.x, f3.y), cvtpk2(f3.z, f3.w)};
    uint4* d = (uint4*)(Xb + (size_t)t * Hdim + l * 16);
    d[0] = *(uint4*)&q[0];
    d[1] = *(uint4*)&q[4];
  }
#pragma unroll
  for (int e = 0; e < Ex; e++) {
#pragma unroll
    for (int off = 32; off > 0; off >>= 1) acc[e] += __shfl_down(acc[e], off);
  }
  if (l == 0) {
    float m = acc[0]; int mi = 0;
#pragma unroll
    for (int e = 1; e < Ex; e++) if (acc[e] > m) { m = acc[e]; mi = e; }  // first-max == jnp.argmax
    float s = 0.f;
#pragma unroll
    for (int e = 0; e < Ex; e++) s += expf(acc[e] - m);
    prob[t]   = 1.0f / s;
    expert[t] = mi;
  }
}

// ---------------- prep: W pre-tiling (QKV + dense) + routing, one launch ----------
// grid (33, 32, 8): x<24 -> QKV wconv tile (ncb=x), 24<=x<32 -> dense tile
// (ncb=x-24), x==32 & y==0 & z==0 -> route (histogram+offsets+tile map+scatter).
// Wt chunk: [e][ncb][kb][F(8)][lane(64)] short8; (F,lane) holds
// W[k=kb*32+8*(lane>>4)+j][col=ncb*128+F*16+(lane&15)] — MFMA B-frag order.
__global__ __launch_bounds__(256) void prep_kernel(
    const float* __restrict__ Wq, const float* __restrict__ Wd,
    unsigned short* __restrict__ WtQ, unsigned short* __restrict__ WtD,
    const int* __restrict__ expert, int* offs, int* meta, int* te, int* tr,
    int* __restrict__ perm) {
  int bx = blockIdx.x, kb = blockIdx.y, e = blockIdx.z;
  int tid = threadIdx.x;

  if (bx == 32) {                       // ---- route branch (one active block) ----
    if (kb != 0 || e != 0) return;
    __shared__ int cnt[Ex];
    __shared__ int cur[Ex];
    if (tid < Ex) cnt[tid] = 0;
    __syncthreads();
    for (int t = tid; t < T; t += 256) atomicAdd(&cnt[expert[t]], 1);
    __syncthreads();
    if (tid == 0) {
      int o = 0, nt = 0;
      for (int ee = 0; ee < Ex; ee++) {
        offs[ee] = o; cur[ee] = o;
        int c = cnt[ee];
        for (int r = 0; r < c; r += 128) { te[nt] = ee; tr[nt] = o + r; nt++; }
        o += c;
      }
      offs[Ex] = o;
      meta[0] = nt;
    }
    __syncthreads();
    for (int t = tid; t < T; t += 256) {
      int slot = atomicAdd(&cur[expert[t]], 1);
      perm[slot] = t;
    }
    return;
  }

  // ---- wconv branch ----
  const float* W;
  unsigned short* Wt;
  int ncb, NCOLS, NCB;
  if (bx < 24) { W = Wq; Wt = WtQ; ncb = bx;      NCOLS = H3;   NCB = 24; }
  else         { W = Wd; Wt = WtD; ncb = bx - 24; NCOLS = Hdim; NCB = 8;  }

  __shared__ float Ls[32 * 132];
  const float* src = W + ((size_t)e * Hdim + kb * 32) * NCOLS + ncb * 128;
  int r = tid >> 3, cb = (tid & 7) * 4;
#pragma unroll
  for (int i = 0; i < 4; i++) {
    float4 v = *(const float4*)(src + (size_t)r * NCOLS + cb + i * 32);
    *(float4*)&Ls[r * 132 + cb + i * 32] = v;
  }
  __syncthreads();
  unsigned short* dst = Wt + (((size_t)e * NCB + ncb) * KB_N + kb) * 4096;
#pragma unroll
  for (int h = 0; h < 2; h++) {
    int c = h * 256 + tid;
    int F = c >> 6, l4c = (c >> 4) & 3, l15c = c & 15;
    const float* col = &Ls[(8 * l4c) * 132 + F * 16 + l15c];
    unsigned q[4];
#pragma unroll
    for (int j = 0; j < 4; j++)
      q[j] = cvtpk2(col[(2 * j) * 132], col[(2 * j + 1) * 132]);
    *(uint4*)(dst + (size_t)c * 8) = *(uint4*)q;
  }
}

// ---------------- grouped GEMM v13 (champion): 2-K-step phases --------------------
// BM=128 BN=64, 4 waves 2x2. Phase = 64 k: one vmcnt(4)+lgkmcnt(0)+barrier,
// 4 gl16 (A next phase -> opposite pair), 8 ds_read_b128, 16 MFMA, 4 B reg
// loads (2-phase lead). A LDS: 2 pairs x 16KB = 32KB.
template <int BN>
__global__ __launch_bounds__(256) void moe_gemm_v13(
    const unsigned short* __restrict__ Xb, const unsigned short* __restrict__ Wt,
    const float* __restrict__ bias, const float* __restrict__ prob,
    const int* __restrict__ perm, const int* __restrict__ offs,
    const int* __restrict__ metap, const int* __restrict__ tile_e,
    const int* __restrict__ tile_r,
    unsigned short* __restrict__ Ybf, float* __restrict__ Yf, int Ncols) {
  constexpr int NF = BN / 32;            // 2 B-frags per wave
  int tIdx = blockIdx.y;
  if (tIdx >= metap[0]) return;
  int e = tile_e[tIdx], row0 = tile_r[tIdx];
  int rows = offs[e + 1] - row0; if (rows > 128) rows = 128;
  int col0 = blockIdx.x * BN;
  int ncb_n = Ncols >> 7;

  __shared__ unsigned short As[2 * 8192];   // [pair][tile 0/1][128*32]
  __shared__ int   tok_s[128];
  __shared__ float p_s[128];

  int tid = threadIdx.x;
  if (tid < 128) {
    int rr = tid < rows ? tid : rows - 1;
    int tok = perm[row0 + rr];
    tok_s[tid] = tok; p_s[tid] = prob[tok];
  }
  __syncthreads();

  int lane = tid & 63, wave = tid >> 6;
  int l15 = lane & 15, l4 = lane >> 4;
  int wr = wave >> 1, wc = wave & 1;
  int aslotr = l4 ^ ((l15 >> 1) & 3);

  // A gather sources (swizzled-slot scheme, verified since r7)
  int arow0 = wave * 16 + (lane >> 2);
  int arow1 = arow0 + 64;
  int aslot0 = (lane & 3) ^ ((arow0 >> 1) & 3);
  int aslot1 = (lane & 3) ^ ((arow1 >> 1) & 3);
  const unsigned short* ag0 = Xb + (size_t)tok_s[arow0] * Hdim + aslot0 * 8;
  const unsigned short* ag1 = Xb + (size_t)tok_s[arow1] * Hdim + aslot1 * 8;

  const unsigned short* btile = Wt + (((size_t)e * ncb_n + (col0 >> 7)) * KB_N) * 4096;
  int Fb = ((col0 & 127) >> 4) + wc * NF;
  const unsigned short* bfrag = btile + ((size_t)(Fb * 64 + lane)) * 8;

  f32x4 acc[4][NF] = {};
  short8 bq[2][2][NF];   // [phase parity][k-tile in phase][frag] — all static

  // ---- prologue: A(phase0)->pair0, B parities 0 (k0,k1) and 1 (k2,k3) ----
  gl16(ag0 + 0 * 32, As + 0 + wave * 512);
  gl16(ag1 + 0 * 32, As + 2048 + wave * 512);
  gl16(ag0 + 1 * 32, As + 4096 + wave * 512);
  gl16(ag1 + 1 * 32, As + 4096 + 2048 + wave * 512);
  asm volatile("" ::: "memory");
#pragma unroll
  for (int t = 0; t < 2; t++)
#pragma unroll
    for (int n = 0; n < NF; n++)
      bq[0][t][n] = *(const short8*)(bfrag + (size_t)t * 4096 + n * 512);
#pragma unroll
  for (int t = 0; t < 2; t++)
#pragma unroll
    for (int n = 0; n < NF; n++)
      bq[1][t][n] = *(const short8*)(bfrag + (size_t)(2 + t) * 4096 + n * 512);
  asm volatile("" ::: "memory");

#define PHASE(PH, PAR)                                                             \
  {                                                                                \
    int kap = ((PH) + 1 < NPH) ? (PH) + 1 : NPH - 1;  /* A stage: next phase */    \
    int kbp = ((PH) + 2 < NPH) ? (PH) + 2 : NPH - 1;  /* B reload: +2 phases */    \
    asm volatile("s_waitcnt vmcnt(4) lgkmcnt(0)" ::: "memory");                    \
    __builtin_amdgcn_s_barrier();                                                  \
    asm volatile("" ::: "memory");                                                 \
    unsigned short* dA = As + ((PAR) ^ 1) * 8192;                                  \
    gl16(ag0 + (size_t)(2 * kap) * 32, dA + wave * 512);                           \
    gl16(ag1 + (size_t)(2 * kap) * 32, dA + 2048 + wave * 512);                    \
    gl16(ag0 + (size_t)(2 * kap + 1) * 32, dA + 4096 + wave * 512);                \
    gl16(ag1 + (size_t)(2 * kap + 1) * 32, dA + 4096 + 2048 + wave * 512);         \
    asm volatile("" ::: "memory");                                                 \
    _Pragma("unroll")                                                              \
    for (int t = 0; t < 2; t++) {                                                  \
      const unsigned short* rb = As + (PAR) * 8192 + t * 4096;                     \
      short8 a[4];                                                                 \
      _Pragma("unroll")                                                            \
      for (int m = 0; m < 4; m++)                                                  \
        a[m] = *(const short8*)&rb[(wr * 64 + m * 16 + l15) * 32 + aslotr * 8];    \
      _Pragma("unroll")                                                            \
      for (int n = 0; n < NF; n++)                                                 \
        _Pragma("unroll")                                                          \
        for (int m = 0; m < 4; m++)                                                \
          acc[m][n] = __builtin_amdgcn_mfma_f32_16x16x32_bf16(                     \
              a[m], bq[PAR][t][n], acc[m][n], 0, 0, 0);                            \
    }                                                                              \
    _Pragma("unroll")                                                              \
    for (int t = 0; t < 2; t++)                                                    \
      _Pragma("unroll")                                                            \
      for (int n = 0; n < NF; n++)                                                 \
        bq[PAR][t][n] =                                                            \
            *(const short8*)(bfrag + (size_t)(2 * kbp + t) * 4096 + n * 512);      \
  }

  for (int ph = 0; ph < NPH; ph += 2) {
    PHASE(ph, 0);
    PHASE(ph + 1, 1);
  }
#undef PHASE
  asm volatile("s_waitcnt vmcnt(0)" ::: "memory");   // drain dummy tail stages

  // epilogue: C/D layout col=lane&15, row=(lane>>4)*4+reg  [m89]
#pragma unroll
  for (int n = 0; n < NF; n++) {
    int colg = col0 + wc * (NF * 16) + n * 16 + l15;
    float bv = bias[(size_t)e * Ncols + colg];
#pragma unroll
    for (int m = 0; m < 4; m++) {
#pragma unroll
      for (int r = 0; r < 4; r++) {
        int row = wr * 64 + m * 16 + l4 * 4 + r;
        if (row < rows) {
          int tok = tok_s[row];
          float o = (acc[m][n][r] + bv) * p_s[row];
          if (Ybf) Ybf[(size_t)tok * Ncols + colg] = f2bf(o);
          else     Yf [(size_t)tok * Ncols + colg] = o;
        }
      }
    }
  }
}

// ---------------- MFMA attention (register-resident softmax) ----------------------
__global__ __launch_bounds__(256) void attn_kernel(
    const unsigned short* __restrict__ qkvb, const int* __restrict__ attn_mask,
    const int* __restrict__ kp_mask, float* __restrict__ probs_out,
    unsigned short* __restrict__ ctxb) {
  int qt = blockIdx.x, h = blockIdx.y, b = blockIdx.z;
  int tid = threadIdx.x;

  __shared__ unsigned short Qs[32 * 72];
  __shared__ unsigned short KV[2][64 * 72];
  __shared__ unsigned short S[32 * 520];
  __shared__ float invs[32];

  int lane = tid & 63, wave = tid >> 6;
  int l15 = lane & 15, l4 = lane >> 4;

  {
    int r = tid >> 3, c = (tid & 7) * 8;
    int t = b * Nseq + qt * 32 + r;
    uint4 v = *(const uint4*)(qkvb + (size_t)t * H3 + h * DHd + c);
    unsigned short* u = (unsigned short*)&v;
    unsigned short tmp[8];
#pragma unroll
    for (int j = 0; j < 8; j++) tmp[j] = f2bf(bf2f(u[j]) * 0.125f);
    *(uint4*)&Qs[r * 72 + c] = *(uint4*)tmp;
  }

  int kr0 = tid >> 3, kc0 = (tid & 7) * 8;
  int kr1 = kr0 + 32;
  const unsigned short* kbase = qkvb + (size_t)(b * Nseq) * H3 + Hdim + h * DHd + kc0;
  uint4 rc0 = *(const uint4*)(kbase + (size_t)kr0 * H3);
  uint4 rc1 = *(const uint4*)(kbase + (size_t)kr1 * H3);
  int cur = 0;
  for (int kt = 0; kt < 8; kt++) {
    int kn = (kt + 1 < 8) ? kt + 1 : 7;
    uint4 nn0 = *(const uint4*)(kbase + (size_t)(kn * 64 + kr0) * H3);
    uint4 nn1 = *(const uint4*)(kbase + (size_t)(kn * 64 + kr1) * H3);
    *(uint4*)&KV[cur][kr0 * 72 + kc0] = rc0;
    *(uint4*)&KV[cur][kr1 * 72 + kc0] = rc1;
    asm volatile("s_waitcnt lgkmcnt(0)" ::: "memory");
    __builtin_amdgcn_s_barrier();
    asm volatile("" ::: "memory");

    f32x4 acc[2] = {};
#pragma unroll
    for (int kk = 0; kk < 2; kk++) {
      short8 bfr = *(const short8*)&KV[cur][(wave * 16 + l15) * 72 + kk * 32 + l4 * 8];
#pragma unroll
      for (int m = 0; m < 2; m++) {
        short8 afr = *(const short8*)&Qs[(m * 16 + l15) * 72 + kk * 32 + l4 * 8];
        acc[m] = __builtin_amdgcn_mfma_f32_16x16x32_bf16(afr, bfr, acc[m], 0, 0, 0);
      }
    }
    int key = kt * 64 + wave * 16 + l15;
#pragma unroll
    for (int m = 0; m < 2; m++) {
#pragma unroll
      for (int r = 0; r < 4; r++) {
        int row = m * 16 + l4 * 4 + r;
        S[row * 520 + key] = f2bf(acc[m][r]);
      }
    }
    rc0 = nn0; rc1 = nn1; cur ^= 1;
  }
  __syncthreads();

  float inv;
  int sr = tid >> 3, sg = tid & 7;
  float sv[8][8];
  {
    unsigned short* Srow = &S[sr * 520];
    const int* amrow = attn_mask + (qt * 32 + sr) * Nseq;
    const int* kprow = kp_mask + b * Nseq;
    float m = -3.0e38f;
#pragma unroll
    for (int i = 0; i < 8; i++) {
      int cb = (sg + 8 * i) * 8;
      uint4 v = *(const uint4*)&Srow[cb];
      unsigned short* u = (unsigned short*)&v;
      int4 a0 = *(const int4*)(amrow + cb);
      int4 a1 = *(const int4*)(amrow + cb + 4);
      int4 k0 = *(const int4*)(kprow + cb);
      int4 k1 = *(const int4*)(kprow + cb + 4);
      sv[i][0] = bf2f(u[0]) + ((a0.x | k0.x) ? -10000.0f : 0.0f);
      sv[i][1] = bf2f(u[1]) + ((a0.y | k0.y) ? -10000.0f : 0.0f);
      sv[i][2] = bf2f(u[2]) + ((a0.z | k0.z) ? -10000.0f : 0.0f);
      sv[i][3] = bf2f(u[3]) + ((a0.w | k0.w) ? -10000.0f : 0.0f);
      sv[i][4] = bf2f(u[4]) + ((a1.x | k1.x) ? -10000.0f : 0.0f);
      sv[i][5] = bf2f(u[5]) + ((a1.y | k1.y) ? -10000.0f : 0.0f);
      sv[i][6] = bf2f(u[6]) + ((a1.z | k1.z) ? -10000.0f : 0.0f);
      sv[i][7] = bf2f(u[7]) + ((a1.w | k1.w) ? -10000.0f : 0.0f);
#pragma unroll
      for (int j = 0; j < 8; j++) m = fmaxf(m, sv[i][j]);
    }
#pragma unroll
    for (int off = 1; off < 8; off <<= 1) m = fmaxf(m, __shfl_xor(m, off));
    float sum = 0.f;
#pragma unroll
    for (int i = 0; i < 8; i++) {
      int cb = (sg + 8 * i) * 8;
      unsigned short t2[8];
#pragma unroll
      for (int j = 0; j < 8; j++) {
        float p = expf(sv[i][j] - m);
        sv[i][j] = p;
        t2[j] = f2bf(p);
        sum += p;
      }
      *(uint4*)&Srow[cb] = *(uint4*)t2;
    }
#pragma unroll
    for (int off = 1; off < 8; off <<= 1) sum += __shfl_xor(sum, off);
    inv = 1.0f / sum;
    if (sg == 0) invs[sr] = inv;
  }
  __syncthreads();

  int kpair = tid & 31, vc = (tid >> 5) * 8;
  const unsigned short* vbase = qkvb + (size_t)(b * Nseq) * H3 + 2 * Hdim + h * DHd + vc;
  uint4 pv0 = *(const uint4*)(vbase + (size_t)(kpair * 2) * H3);
  uint4 pv1 = *(const uint4*)(vbase + (size_t)(kpair * 2 + 1) * H3);

  {
    float* dst = probs_out + (((size_t)(b * NHd + h) * Nseq + qt * 32 + sr) * Nseq);
#pragma unroll
    for (int i = 0; i < 8; i++) {
      int cb = (sg + 8 * i) * 8;
      float4 o0 = {sv[i][0] * inv, sv[i][1] * inv, sv[i][2] * inv, sv[i][3] * inv};
      float4 o1 = {sv[i][4] * inv, sv[i][5] * inv, sv[i][6] * inv, sv[i][7] * inv};
      *(float4*)(dst + cb)     = o0;
      *(float4*)(dst + cb + 4) = o1;
    }
  }

  f32x4 acc2[2] = {};
  cur = 0;
  for (int kt = 0; kt < 8; kt++) {
    int kn = (kt + 1 < 8) ? kt + 1 : 7;
    uint4 nv0 = *(const uint4*)(vbase + (size_t)(kn * 64 + kpair * 2) * H3);
    uint4 nv1 = *(const uint4*)(vbase + (size_t)(kn * 64 + kpair * 2 + 1) * H3);
    unsigned* a0 = (unsigned*)&pv0;
    unsigned* a1 = (unsigned*)&pv1;
#pragma unroll
    for (int i = 0; i < 4; i++) {
      unsigned lo = (a0[i] & 0xffffu) | (a1[i] << 16);
      unsigned hi = (a0[i] >> 16) | (a1[i] & 0xffff0000u);
      *(unsigned*)&KV[cur][(vc + 2 * i    ) * 72 + 2 * kpair] = lo;   // Vt[d][keypair]
      *(unsigned*)&KV[cur][(vc + 2 * i + 1) * 72 + 2 * kpair] = hi;
    }
    asm volatile("s_waitcnt lgkmcnt(0)" ::: "memory");
    __builtin_amdgcn_s_barrier();
    asm volatile("" ::: "memory");
#pragma unroll
    for (int kk = 0; kk < 2; kk++) {
      short8 bfr = *(const short8*)&KV[cur][(wave * 16 + l15) * 72 + kk * 32 + l4 * 8];
#pragma unroll
      for (int m = 0; m < 2; m++) {
        short8 pfr = *(const short8*)&S[(m * 16 + l15) * 520 + kt * 64 + kk * 32 + l4 * 8];
        acc2[m] = __builtin_amdgcn_mfma_f32_16x16x32_bf16(pfr, bfr, acc2[m], 0, 0, 0);
      }
    }
    pv0 = nv0; pv1 = nv1; cur ^= 1;
  }
#pragma unroll
  for (int m = 0; m < 2; m++) {
#pragma unroll
    for (int r = 0; r < 4; r++) {
      int row = m * 16 + l4 * 4 + r;
      int tq = b * Nseq + qt * 32 + row;
      ctxb[(size_t)tq * Hdim + h * DHd + wave * 16 + l15] = f2bf(acc2[m][r] * invs[row]);
    }
  }
}

// ---------------- host ------------------------------------------------------------
extern "C" void kernel_launch(void* const* d_in, const int* in_sizes, int n_in,
                              void* d_out, int out_size, void* d_ws, size_t ws_size,
                              hipStream_t stream) {
  const float* hidden   = (const float*)d_in[0];
  const int*   attn_m   = (const int*)d_in[1];
  const int*   kp_m     = (const int*)d_in[2];
  const float* w_gate   = (const float*)d_in[3];
  const float* w_qkv    = (const float*)d_in[4];
  const float* b_qkv    = (const float*)d_in[5];
  const float* w_dense  = (const float*)d_in[6];
  const float* b_dense  = (const float*)d_in[7];

  float* out       = (float*)d_out;                 // [T,H] fp32
  float* probs_out = out + (size_t)T * Hdim;        // [B,NH,N,N] fp32 (67 MB)

  // WtQ (50.3 MB) borrows the probs region: built+consumed BEFORE attn writes probs.
  unsigned short* WtQ = (unsigned short*)probs_out;

  float*          prob = (float*)d_ws;
  unsigned short* Xb   = (unsigned short*)(prob + 2048);
  unsigned short* qkvb = Xb + (size_t)T * Hdim;
  unsigned short* ctxb = qkvb + (size_t)T * H3;
  unsigned short* WtD  = ctxb + (size_t)T * Hdim;   // 16.8 MB
  int*   ip     = (int*)(WtD + (size_t)Ex * Hdim * Hdim);
  int*   expert = ip;
  int*   perm   = ip + T;
  int*   offs   = ip + 2 * T;
  int*   meta   = offs + 12;
  int*   te     = meta + 4;
  int*   tr     = te + MAXT128;

  gate_kernel<<<T, 64, 0, stream>>>(hidden, w_gate, prob, expert, Xb);
  prep_kernel<<<dim3(33, KB_N, Ex), 256, 0, stream>>>(
      w_qkv, w_dense, WtQ, WtD, expert, offs, meta, te, tr, perm);
  moe_gemm_v13<64><<<dim3(H3 / 64, MAXT128), 256, 0, stream>>>(
      Xb, WtQ, b_qkv, prob, perm, offs, meta, te, tr, qkvb, nullptr, H3);
  attn_kernel<<<dim3(16, NHd, Bsz), 256, 0, stream>>>(qkvb, attn_m, kp_m, probs_out, ctxb);
  moe_gemm_v13<64><<<dim3(Hdim / 64, MAXT128), 256, 0, stream>>>(
      ctxb, WtD, b_dense, prob, perm, offs, meta, te, tr, nullptr, out, Hdim);
}